// Round 8
// baseline (1860.152 us; speedup 1.0000x reference)
//
#include <hip/hip_runtime.h>
#include <hip/hip_fp16.h>

#define NN 50000
#define NEG_SLOPE 0.2f
#define BSHIFT 9
#define BNODES (1 << BSHIFT)                          // 512 nodes per bucket
#define NBUCK ((NN + BNODES - 1) >> BSHIFT)           // 98
#define BCAP 18432                                    // E/NBUCK=16327, +16 sigma
#define NGB ((NN + 31) / 32)                          // gemm1 blocks (32 rows each)

// ---- init: bucket cursors to region starts ----
__global__ void zero_kernel(unsigned* bucket_cursor) {
    int i = threadIdx.x;
    if (i < NBUCK) bucket_cursor[i] = (unsigned)(i * BCAP);
}

// ==== hybrid: blockIdx < nbb -> bucketA (bin edges by dst>>9); else gemm1 ====
__global__ __launch_bounds__(1024) void hybrid_kernel(
        const int* __restrict__ src, const int* __restrict__ dst,
        unsigned* __restrict__ bucket_cursor, int2* __restrict__ ebuf, int E, int nbb,
        const float* __restrict__ h, const float* __restrict__ W1,
        const float* __restrict__ al1, const float* __restrict__ ar1,
        __half* __restrict__ z1h, float* __restrict__ el1, float* __restrict__ er1, int N) {
    __shared__ float smem[32 * 128];   // 16KB union
    int tid = threadIdx.x;
    if (blockIdx.x < nbb) {
        // ---------------- bucketA ----------------
        unsigned* hist = (unsigned*)smem;
        if (tid < NBUCK) hist[tid] = 0u;
        __syncthreads();
        int e = blockIdx.x * 1024 + tid;
        int s = 0, d = 0, b = 0;
        bool valid = e < E;
        if (valid) {
            s = src[e]; d = dst[e]; b = d >> BSHIFT;
            atomicAdd(&hist[b], 1u);
        }
        __syncthreads();
        if (tid < NBUCK) {
            unsigned c = hist[tid];
            hist[tid] = c ? atomicAdd(&bucket_cursor[tid], c) : 0u;
        }
        __syncthreads();
        if (valid) {
            unsigned slot = atomicAdd(&hist[b], 1u);
            ebuf[slot] = make_int2(s, d);
        }
    } else {
        // ---------------- gemm1: 32 rows/block, 8 row-groups x 128 cols ----------------
        float* hs = smem;
        int gb = blockIdx.x - nbb;
        int col = tid & 127, rg = tid >> 7;
        int row0 = gb * 32;
        int nrow = min(32, N - row0);
        const float4* hv = (const float4*)(h + (size_t)row0 * 128);
        float4* hsv = (float4*)hs;
        if (tid < nrow * 32) hsv[tid] = hv[tid];
        __syncthreads();
        float acc[4] = {0.f, 0.f, 0.f, 0.f};
        for (int k = 0; k < 128; k += 4) {
            float w0 = W1[k * 128 + col];
            float w1 = W1[(k + 1) * 128 + col];
            float w2 = W1[(k + 2) * 128 + col];
            float w3 = W1[(k + 3) * 128 + col];
            #pragma unroll
            for (int r = 0; r < 4; ++r) {
                float4 hr = *(const float4*)&hs[(rg * 4 + r) * 128 + k];
                acc[r] = fmaf(hr.x, w0, fmaf(hr.y, w1, fmaf(hr.z, w2, fmaf(hr.w, w3, acc[r]))));
            }
        }
        float a = al1[col], bb = ar1[col];
        int head = col >> 5, lane32 = col & 31;
        #pragma unroll
        for (int r = 0; r < 4; ++r) {
            int rr = rg * 4 + r;
            float pl = acc[r] * a, pr = acc[r] * bb;
            #pragma unroll
            for (int o = 16; o; o >>= 1) {
                pl += __shfl_xor(pl, o, 32);
                pr += __shfl_xor(pr, o, 32);
            }
            if (rr < nrow) {
                int row = row0 + rr;
                z1h[(size_t)row * 128 + col] = __float2half(acc[r]);
                if (lane32 == 0) {
                    el1[row * 4 + head] = pl;
                    er1[row * 4 + head] = pr;
                }
            }
        }
    }
}

// ---- scatterC: inline bucket scan + per-bucket LDS hist/scan/rank;
//      writes off[], src_sorted[], and per-edge alpha1 (exp of leaky score, 4 heads) ----
__global__ __launch_bounds__(1024) void scatterC(
        const int2* __restrict__ ebuf, const unsigned* __restrict__ bucket_cursor,
        const float* __restrict__ el1, const float* __restrict__ er1,
        unsigned* __restrict__ off, int* __restrict__ src_sorted,
        float4* __restrict__ alpha1v, int N, int E) {
    __shared__ unsigned hist[BNODES], nodeoff[BNODES], wsum[8], bsz[128];
    __shared__ float4 er_s[BNODES];
    int b = blockIdx.x, tid = threadIdx.x;
    int base = b << BSHIFT;
    unsigned rs = (unsigned)(b * BCAP), re = bucket_cursor[b];
    const float4* el1v = (const float4*)el1;
    const float4* er1v = (const float4*)er1;

    // inline exclusive scan of bucket sizes (98 values, serial on tid0 over LDS)
    if (tid < 128) bsz[tid] = (tid < NBUCK) ? bucket_cursor[tid] - (unsigned)(tid * BCAP) : 0u;
    if (tid < BNODES) {
        hist[tid] = 0u;
        int n = base + tid;
        er_s[tid] = (n < N) ? er1v[n] : make_float4(0.f, 0.f, 0.f, 0.f);
    }
    __syncthreads();
    if (tid == 0) {
        unsigned r = 0;
        for (int t = 0; t < NBUCK; ++t) { unsigned c = bsz[t]; bsz[t] = r; r += c; }
        if (b == 0) off[N] = (unsigned)E;
    }
    __syncthreads();
    unsigned boff = bsz[b];

    // per-node histogram
    for (unsigned i = rs + tid; i < re; i += 1024)
        atomicAdd(&hist[ebuf[i].y - base], 1u);
    __syncthreads();
    // scan hist -> nodeoff
    unsigned v = 0, x = 0;
    int lane = tid & 63, wv = tid >> 6;
    if (tid < BNODES) {
        v = hist[tid]; x = v;
        #pragma unroll
        for (int o = 1; o < 64; o <<= 1) {
            unsigned n = __shfl_up(x, o, 64);
            if (lane >= o) x += n;
        }
        if (lane == 63) wsum[wv] = x;
    }
    __syncthreads();
    if (tid == 0) {
        unsigned r = 0;
        #pragma unroll
        for (int k = 0; k < 8; ++k) { unsigned t = wsum[k]; wsum[k] = r; r += t; }
    }
    __syncthreads();
    if (tid < BNODES) {
        unsigned exoff = x - v + wsum[wv] + boff;
        nodeoff[tid] = exoff;
        if (base + tid < N) off[base + tid] = exoff;
        hist[tid] = 0u;
    }
    __syncthreads();
    // rank + write src_sorted and alpha (exp of leaky score; softmax shift dropped:
    // scores bounded |e|<~4, exp-safe, softmax shift-invariant)
    for (unsigned i = rs + tid; i < re; i += 1024) {
        int2 ed = ebuf[i];
        int ln = ed.y - base;
        unsigned r = atomicAdd(&hist[ln], 1u);
        unsigned p = nodeoff[ln] + r;
        src_sorted[p] = ed.x;
        float4 el = el1v[ed.x];
        float4 er = er_s[ln];
        float v0 = el.x + er.x; v0 = v0 > 0.f ? v0 : NEG_SLOPE * v0;
        float v1 = el.y + er.y; v1 = v1 > 0.f ? v1 : NEG_SLOPE * v1;
        float v2 = el.z + er.z; v2 = v2 > 0.f ? v2 : NEG_SLOPE * v2;
        float v3 = el.w + er.w; v3 = v3 > 0.f ? v3 : NEG_SLOPE * v3;
        alpha1v[p] = make_float4(__expf(v0), __expf(v1), __expf(v2), __expf(v3));
    }
}

// ====== layer1: pure SpMM (alpha precomputed, position-indexed) + elu + gemm2 ======
__global__ __launch_bounds__(256) void agg1_fused(
        const int* __restrict__ src_sorted, const unsigned* __restrict__ off,
        const float* __restrict__ alpha1, const __half* __restrict__ z1h,
        const float* __restrict__ b1, const float* __restrict__ W2,
        const float* __restrict__ al2, const float* __restrict__ ar2,
        __half* __restrict__ z2h, float* __restrict__ el2, float* __restrict__ er2) {
    __shared__ float W2s[128 * 32];
    __shared__ float xs[4][128];
    int tid = threadIdx.x, lane = tid & 63, w = tid >> 6;
    {
        const float4* s4 = (const float4*)W2;
        float4* d4 = (float4*)W2s;
        #pragma unroll
        for (int k = 0; k < 4; ++k) d4[tid + 256 * k] = s4[tid + 256 * k];
    }

    int node = blockIdx.x * 4 + w;
    int start = (int)off[node], end = (int)off[node + 1];
    int g = lane >> 4, l16 = lane & 15, head = l16 >> 2, j = l16 & 3;

    float acc[8];
    #pragma unroll
    for (int jj = 0; jj < 8; ++jj) acc[jj] = 0.f;
    float sloc = 0.f;
    int endm1 = end - 1;
    for (int base = start; base < end; base += 32) {
        #pragma unroll
        for (int t = 0; t < 8; ++t) {               // 32 edges in flight per wave-iter
            int i = base + 4 * t + g;
            int ic = min(i, endm1);                 // clamped: always valid
            int s = src_sorted[ic];
            float a = alpha1[ic * 4 + head];        // position-indexed: independent of s
            a = (i < end) ? a : 0.f;                // select, not branch
            sloc += (j == 0) ? a : 0.f;
            float4 r = *(const float4*)(z1h + ((size_t)s << 7) + l16 * 8);
            const __half* zh = (const __half*)&r;
            #pragma unroll
            for (int k = 0; k < 8; ++k)             // v_fma_mix_f32
                acc[k] = fmaf(__half2float(zh[k]), a, acc[k]);
        }
    }
    #pragma unroll
    for (int jj = 0; jj < 8; ++jj) {
        acc[jj] += __shfl_xor(acc[jj], 16, 64);
        acc[jj] += __shfl_xor(acc[jj], 32, 64);
    }
    sloc += __shfl_xor(sloc, 1, 64);
    sloc += __shfl_xor(sloc, 2, 64);
    sloc += __shfl_xor(sloc, 16, 64);
    sloc += __shfl_xor(sloc, 32, 64);
    float inv = sloc > 0.f ? 1.f / sloc : 0.f;

    if (g == 0) {
        #pragma unroll
        for (int jj = 0; jj < 8; ++jj) {
            float x = acc[jj] * inv + b1[l16 * 8 + jj];
            x = x > 0.f ? x : (__expf(x) - 1.f);   // elu
            xs[w][l16 * 8 + jj] = x;
        }
    }
    __syncthreads();   // covers W2s staging + xs

    int c = lane & 31, q = lane >> 5;
    float p = 0.f;
    for (int kk = 0; kk < 64; kk += 4) {
        int k = q * 64 + kk;
        float4 xv = *(const float4*)&xs[w][k];     // ds_read_b128
        p = fmaf(xv.x, W2s[k * 32 + c],
            fmaf(xv.y, W2s[(k + 1) * 32 + c],
            fmaf(xv.z, W2s[(k + 2) * 32 + c],
            fmaf(xv.w, W2s[(k + 3) * 32 + c], p))));
    }
    p += __shfl_xor(p, 32, 64);
    if (lane < 32) {
        z2h[(size_t)node * 32 + c] = __float2half(p);
        float pl = p * al2[c], pr = p * ar2[c];
        #pragma unroll
        for (int o = 16; o; o >>= 1) {
            pl += __shfl_xor(pl, o, 32);
            pr += __shfl_xor(pr, o, 32);
        }
        if (c == 0) { el2[node] = pl; er2[node] = pr; }
    }
}

// ====== layer2: single-pass exp + SpMM (fma_mix) + bias -> out (wave/node) ======
__global__ __launch_bounds__(256) void agg2_fused(
        const int* __restrict__ src_sorted, const unsigned* __restrict__ off,
        const float* __restrict__ el2, const float* __restrict__ er2,
        const __half* __restrict__ z2h, const float* __restrict__ b2,
        float* __restrict__ out) {
    int tid = threadIdx.x, lane = tid & 63;
    int node = blockIdx.x * 4 + (tid >> 6);
    int start = (int)off[node], end = (int)off[node + 1];
    float er_d = er2[node];

    int g = lane >> 2, l4 = lane & 3;
    float acc[8];
    #pragma unroll
    for (int jj = 0; jj < 8; ++jj) acc[jj] = 0.f;
    float sloc = 0.f;
    int endm1 = end - 1;
    for (int base = start; base < end; base += 64) {
        #pragma unroll
        for (int t = 0; t < 4; ++t) {               // 64 edges in flight per wave-iter
            int i = base + 16 * t + g;
            int ic = min(i, endm1);
            int s = src_sorted[ic];
            float v = el2[s] + er_d;
            v = v > 0.f ? v : NEG_SLOPE * v;
            float ex = __expf(v);
            ex = (i < end) ? ex : 0.f;
            sloc += (l4 == 0) ? ex : 0.f;
            float4 r = *(const float4*)(z2h + ((size_t)s << 5) + l4 * 8);
            const __half* zh = (const __half*)&r;
            #pragma unroll
            for (int k = 0; k < 8; ++k)
                acc[k] = fmaf(__half2float(zh[k]), ex, acc[k]);
        }
    }
    #pragma unroll
    for (int jj = 0; jj < 8; ++jj) {
        acc[jj] += __shfl_xor(acc[jj], 4, 64);
        acc[jj] += __shfl_xor(acc[jj], 8, 64);
        acc[jj] += __shfl_xor(acc[jj], 16, 64);
        acc[jj] += __shfl_xor(acc[jj], 32, 64);
    }
    #pragma unroll
    for (int o = 32; o; o >>= 1) sloc += __shfl_xor(sloc, o, 64);
    float inv = sloc > 0.f ? 1.f / sloc : 0.f;
    if (g == 0) {
        #pragma unroll
        for (int jj = 0; jj < 8; ++jj)
            out[(size_t)node * 32 + l4 * 8 + jj] = acc[jj] * inv + b2[l4 * 8 + jj];
    }
}

extern "C" void kernel_launch(void* const* d_in, const int* in_sizes, int n_in,
                              void* d_out, int out_size, void* d_ws, size_t ws_size,
                              hipStream_t stream) {
    const float* h   = (const float*)d_in[0];
    const int*   src = (const int*)d_in[1];
    const int*   dst = (const int*)d_in[2];
    const float* W1  = (const float*)d_in[3];
    const float* al1 = (const float*)d_in[4];
    const float* ar1 = (const float*)d_in[5];
    const float* b1  = (const float*)d_in[6];
    const float* W2  = (const float*)d_in[7];
    const float* al2 = (const float*)d_in[8];
    const float* ar2 = (const float*)d_in[9];
    const float* b2  = (const float*)d_in[10];
    float* out = (float*)d_out;
    const int N = NN;
    const int E = in_sizes[1];
    const int nbb = (E + 1023) / 1024;

    char* w = (char*)d_ws;
    __half* z1h       = (__half*)w;   w += (size_t)N * 128 * 2;
    __half* z2h       = (__half*)w;   w += (size_t)N * 32 * 2;
    int2*  ebuf       = (int2*)w;     w += (size_t)NBUCK * BCAP * 8;
    float4* alpha1v   = (float4*)w;   w += (size_t)E * 16;
    int*   src_sorted = (int*)w;      w += (size_t)E * 4;
    float* el1        = (float*)w;    w += (size_t)N * 4 * 4;
    float* er1        = (float*)w;    w += (size_t)N * 4 * 4;
    float* el2        = (float*)w;    w += (size_t)N * 4;
    float* er2        = (float*)w;    w += (size_t)N * 4;
    unsigned* off     = (unsigned*)w; w += (size_t)(N + 16) * 4;
    unsigned* bucket_cursor = (unsigned*)w; w += 128 * 4;

    zero_kernel<<<1, 128, 0, stream>>>(bucket_cursor);
    hybrid_kernel<<<nbb + NGB, 1024, 0, stream>>>(src, dst, bucket_cursor, ebuf, E, nbb,
                                                  h, W1, al1, ar1, z1h, el1, er1, N);
    scatterC<<<NBUCK, 1024, 0, stream>>>(ebuf, bucket_cursor, el1, er1,
                                         off, src_sorted, alpha1v, N, E);
    agg1_fused<<<N / 4, 256, 0, stream>>>(src_sorted, off, (const float*)alpha1v, z1h, b1,
                                          W2, al2, ar2, z2h, el2, er2);
    agg2_fused<<<N / 4, 256, 0, stream>>>(src_sorted, off, el2, er2, z2h, b2, out);
}

// Round 9
// 340.308 us; speedup vs baseline: 5.4661x; 5.4661x over previous
//
#include <hip/hip_runtime.h>
#include <hip/hip_fp16.h>

#define NN 50000
#define NEG_SLOPE 0.2f
#define BSHIFT 9
#define BNODES (1 << BSHIFT)                          // 512 nodes per bucket
#define NBUCK ((NN + BNODES - 1) >> BSHIFT)           // 98
#define BCAP 18432                                    // E/NBUCK=16384 avg, +16 sigma

// ---- init: bucket cursors to region starts ----
__global__ void zero_kernel(unsigned* bucket_cursor) {
    int i = threadIdx.x;
    if (i < NBUCK) bucket_cursor[i] = (unsigned)(i * BCAP);
}

// ---- pass A: coarse bucket binning of (src,dst) by dst>>9 (low regs, no spill) ----
__global__ __launch_bounds__(1024) void bucketA(
        const int* __restrict__ src, const int* __restrict__ dst,
        unsigned* __restrict__ bucket_cursor, int2* __restrict__ ebuf, int E) {
    __shared__ unsigned hist[NBUCK];
    int tid = threadIdx.x;
    if (tid < NBUCK) hist[tid] = 0u;
    __syncthreads();
    int e = blockIdx.x * 1024 + tid;
    int s = 0, d = 0, b = 0;
    bool valid = e < E;
    if (valid) {
        s = src[e]; d = dst[e]; b = d >> BSHIFT;
        atomicAdd(&hist[b], 1u);
    }
    __syncthreads();
    if (tid < NBUCK) {
        unsigned c = hist[tid];
        hist[tid] = c ? atomicAdd(&bucket_cursor[tid], c) : 0u;
    }
    __syncthreads();
    if (valid) {
        unsigned slot = atomicAdd(&hist[b], 1u);
        ebuf[slot] = make_int2(s, d);
    }
}

// ===== z1 = h @ W1 (fp16 out), fused el1/er1 — 128 threads, full VGPR headroom =====
#define TM 32
__global__ __launch_bounds__(128) void gemm1_kernel(
        const float* __restrict__ h, const float* __restrict__ W1,
        const float* __restrict__ al1, const float* __restrict__ ar1,
        __half* __restrict__ z1h, float* __restrict__ el1, float* __restrict__ er1, int N) {
    __shared__ float hs[TM * 128];
    int tid = threadIdx.x;
    int row0 = blockIdx.x * TM;
    int nrow = min(TM, N - row0);
    const float4* hv = (const float4*)(h + (size_t)row0 * 128);
    float4* hsv = (float4*)hs;
    for (int idx = tid; idx < nrow * 32; idx += 128) hsv[idx] = hv[idx];
    __syncthreads();
    float acc[TM];
    #pragma unroll
    for (int r = 0; r < TM; ++r) acc[r] = 0.f;
    for (int k = 0; k < 128; k += 4) {
        float w0 = W1[k * 128 + tid];
        float w1 = W1[(k + 1) * 128 + tid];
        float w2 = W1[(k + 2) * 128 + tid];
        float w3 = W1[(k + 3) * 128 + tid];
        #pragma unroll
        for (int r = 0; r < TM; ++r) {
            float4 hr = *(const float4*)&hs[r * 128 + k];   // broadcast b128
            acc[r] = fmaf(hr.x, w0, fmaf(hr.y, w1, fmaf(hr.z, w2, fmaf(hr.w, w3, acc[r]))));
        }
    }
    float a = al1[tid], b = ar1[tid];
    int head = tid >> 5, lane32 = tid & 31;
    #pragma unroll
    for (int r = 0; r < TM; ++r) {
        float pl = acc[r] * a, pr = acc[r] * b;
        #pragma unroll
        for (int o = 16; o; o >>= 1) {
            pl += __shfl_xor(pl, o, 32);
            pr += __shfl_xor(pr, o, 32);
        }
        if (r < nrow) {
            z1h[(size_t)(row0 + r) * 128 + tid] = __float2half(acc[r]);
            if (lane32 == 0) {
                el1[(row0 + r) * 4 + head] = pl;
                er1[(row0 + r) * 4 + head] = pr;
            }
        }
    }
}

// ---- scatterC: inline bucket scan + per-bucket LDS hist/scan/rank;
//      writes off[], src_sorted[], and per-edge alpha1 (exp of leaky score, 4 heads) ----
__global__ __launch_bounds__(1024) void scatterC(
        const int2* __restrict__ ebuf, const unsigned* __restrict__ bucket_cursor,
        const float* __restrict__ el1, const float* __restrict__ er1,
        unsigned* __restrict__ off, int* __restrict__ src_sorted,
        float4* __restrict__ alpha1v, int N, int E) {
    __shared__ unsigned hist[BNODES], nodeoff[BNODES], wsum[8], bsz[128];
    __shared__ float4 er_s[BNODES];
    int b = blockIdx.x, tid = threadIdx.x;
    int base = b << BSHIFT;
    unsigned rs = (unsigned)(b * BCAP), re = bucket_cursor[b];
    const float4* el1v = (const float4*)el1;
    const float4* er1v = (const float4*)er1;

    // inline exclusive scan of bucket sizes (98 values, serial on tid0 over LDS)
    if (tid < 128) bsz[tid] = (tid < NBUCK) ? bucket_cursor[tid] - (unsigned)(tid * BCAP) : 0u;
    if (tid < BNODES) {
        hist[tid] = 0u;
        int n = base + tid;
        er_s[tid] = (n < N) ? er1v[n] : make_float4(0.f, 0.f, 0.f, 0.f);
    }
    __syncthreads();
    if (tid == 0) {
        unsigned r = 0;
        for (int t = 0; t < NBUCK; ++t) { unsigned c = bsz[t]; bsz[t] = r; r += c; }
        if (b == 0) off[N] = (unsigned)E;
    }
    __syncthreads();
    unsigned boff = bsz[b];

    // per-node histogram
    for (unsigned i = rs + tid; i < re; i += 1024)
        atomicAdd(&hist[ebuf[i].y - base], 1u);
    __syncthreads();
    // scan hist -> nodeoff
    unsigned v = 0, x = 0;
    int lane = tid & 63, wv = tid >> 6;
    if (tid < BNODES) {
        v = hist[tid]; x = v;
        #pragma unroll
        for (int o = 1; o < 64; o <<= 1) {
            unsigned n = __shfl_up(x, o, 64);
            if (lane >= o) x += n;
        }
        if (lane == 63) wsum[wv] = x;
    }
    __syncthreads();
    if (tid == 0) {
        unsigned r = 0;
        #pragma unroll
        for (int k = 0; k < 8; ++k) { unsigned t = wsum[k]; wsum[k] = r; r += t; }
    }
    __syncthreads();
    if (tid < BNODES) {
        unsigned exoff = x - v + wsum[wv] + boff;
        nodeoff[tid] = exoff;
        if (base + tid < N) off[base + tid] = exoff;
        hist[tid] = 0u;
    }
    __syncthreads();
    // rank + write src_sorted and alpha (exp of leaky score; softmax shift dropped:
    // scores bounded |e|<~4, exp-safe, softmax shift-invariant)
    for (unsigned i = rs + tid; i < re; i += 1024) {
        int2 ed = ebuf[i];
        int ln = ed.y - base;
        unsigned r = atomicAdd(&hist[ln], 1u);
        unsigned p = nodeoff[ln] + r;
        src_sorted[p] = ed.x;
        float4 el = el1v[ed.x];
        float4 er = er_s[ln];
        float v0 = el.x + er.x; v0 = v0 > 0.f ? v0 : NEG_SLOPE * v0;
        float v1 = el.y + er.y; v1 = v1 > 0.f ? v1 : NEG_SLOPE * v1;
        float v2 = el.z + er.z; v2 = v2 > 0.f ? v2 : NEG_SLOPE * v2;
        float v3 = el.w + er.w; v3 = v3 > 0.f ? v3 : NEG_SLOPE * v3;
        alpha1v[p] = make_float4(__expf(v0), __expf(v1), __expf(v2), __expf(v3));
    }
}

// ====== layer1: pure SpMM (alpha precomputed, position-indexed) + elu + gemm2 ======
__global__ __launch_bounds__(256) void agg1_fused(
        const int* __restrict__ src_sorted, const unsigned* __restrict__ off,
        const float* __restrict__ alpha1, const __half* __restrict__ z1h,
        const float* __restrict__ b1, const float* __restrict__ W2,
        const float* __restrict__ al2, const float* __restrict__ ar2,
        __half* __restrict__ z2h, float* __restrict__ el2, float* __restrict__ er2) {
    __shared__ float W2s[128 * 32];
    __shared__ float xs[4][128];
    int tid = threadIdx.x, lane = tid & 63, w = tid >> 6;
    {
        const float4* s4 = (const float4*)W2;
        float4* d4 = (float4*)W2s;
        #pragma unroll
        for (int k = 0; k < 4; ++k) d4[tid + 256 * k] = s4[tid + 256 * k];
    }

    int node = blockIdx.x * 4 + w;
    int start = (int)off[node], end = (int)off[node + 1];
    int g = lane >> 4, l16 = lane & 15, head = l16 >> 2, j = l16 & 3;

    float acc[8];
    #pragma unroll
    for (int jj = 0; jj < 8; ++jj) acc[jj] = 0.f;
    float sloc = 0.f;
    int endm1 = end - 1;
    for (int base = start; base < end; base += 32) {
        #pragma unroll
        for (int t = 0; t < 8; ++t) {               // 32 edges in flight per wave-iter
            int i = base + 4 * t + g;
            int ic = min(i, endm1);                 // clamped: always valid
            int s = src_sorted[ic];
            float a = alpha1[ic * 4 + head];        // position-indexed: independent of s
            a = (i < end) ? a : 0.f;                // select, not branch
            sloc += (j == 0) ? a : 0.f;
            float4 r = *(const float4*)(z1h + ((size_t)s << 7) + l16 * 8);
            const __half* zh = (const __half*)&r;
            #pragma unroll
            for (int k = 0; k < 8; ++k)             // v_fma_mix_f32
                acc[k] = fmaf(__half2float(zh[k]), a, acc[k]);
        }
    }
    #pragma unroll
    for (int jj = 0; jj < 8; ++jj) {
        acc[jj] += __shfl_xor(acc[jj], 16, 64);
        acc[jj] += __shfl_xor(acc[jj], 32, 64);
    }
    sloc += __shfl_xor(sloc, 1, 64);
    sloc += __shfl_xor(sloc, 2, 64);
    sloc += __shfl_xor(sloc, 16, 64);
    sloc += __shfl_xor(sloc, 32, 64);
    float inv = sloc > 0.f ? 1.f / sloc : 0.f;

    if (g == 0) {
        #pragma unroll
        for (int jj = 0; jj < 8; ++jj) {
            float x = acc[jj] * inv + b1[l16 * 8 + jj];
            x = x > 0.f ? x : (__expf(x) - 1.f);   // elu
            xs[w][l16 * 8 + jj] = x;
        }
    }
    __syncthreads();   // covers W2s staging + xs

    int c = lane & 31, q = lane >> 5;
    float p = 0.f;
    for (int kk = 0; kk < 64; kk += 4) {
        int k = q * 64 + kk;
        float4 xv = *(const float4*)&xs[w][k];     // ds_read_b128
        p = fmaf(xv.x, W2s[k * 32 + c],
            fmaf(xv.y, W2s[(k + 1) * 32 + c],
            fmaf(xv.z, W2s[(k + 2) * 32 + c],
            fmaf(xv.w, W2s[(k + 3) * 32 + c], p))));
    }
    p += __shfl_xor(p, 32, 64);
    if (lane < 32) {
        z2h[(size_t)node * 32 + c] = __float2half(p);
        float pl = p * al2[c], pr = p * ar2[c];
        #pragma unroll
        for (int o = 16; o; o >>= 1) {
            pl += __shfl_xor(pl, o, 32);
            pr += __shfl_xor(pr, o, 32);
        }
        if (c == 0) { el2[node] = pl; er2[node] = pr; }
    }
}

// ====== layer2: single-pass exp + SpMM (fma_mix) + bias -> out (wave/node) ======
__global__ __launch_bounds__(256) void agg2_fused(
        const int* __restrict__ src_sorted, const unsigned* __restrict__ off,
        const float* __restrict__ el2, const float* __restrict__ er2,
        const __half* __restrict__ z2h, const float* __restrict__ b2,
        float* __restrict__ out) {
    int tid = threadIdx.x, lane = tid & 63;
    int node = blockIdx.x * 4 + (tid >> 6);
    int start = (int)off[node], end = (int)off[node + 1];
    float er_d = er2[node];

    int g = lane >> 2, l4 = lane & 3;
    float acc[8];
    #pragma unroll
    for (int jj = 0; jj < 8; ++jj) acc[jj] = 0.f;
    float sloc = 0.f;
    int endm1 = end - 1;
    for (int base = start; base < end; base += 64) {
        #pragma unroll
        for (int t = 0; t < 4; ++t) {               // 64 edges in flight per wave-iter
            int i = base + 16 * t + g;
            int ic = min(i, endm1);
            int s = src_sorted[ic];
            float v = el2[s] + er_d;
            v = v > 0.f ? v : NEG_SLOPE * v;
            float ex = __expf(v);
            ex = (i < end) ? ex : 0.f;
            sloc += (l4 == 0) ? ex : 0.f;
            float4 r = *(const float4*)(z2h + ((size_t)s << 5) + l4 * 8);
            const __half* zh = (const __half*)&r;
            #pragma unroll
            for (int k = 0; k < 8; ++k)
                acc[k] = fmaf(__half2float(zh[k]), ex, acc[k]);
        }
    }
    #pragma unroll
    for (int jj = 0; jj < 8; ++jj) {
        acc[jj] += __shfl_xor(acc[jj], 4, 64);
        acc[jj] += __shfl_xor(acc[jj], 8, 64);
        acc[jj] += __shfl_xor(acc[jj], 16, 64);
        acc[jj] += __shfl_xor(acc[jj], 32, 64);
    }
    #pragma unroll
    for (int o = 32; o; o >>= 1) sloc += __shfl_xor(sloc, o, 64);
    float inv = sloc > 0.f ? 1.f / sloc : 0.f;
    if (g == 0) {
        #pragma unroll
        for (int jj = 0; jj < 8; ++jj)
            out[(size_t)node * 32 + l4 * 8 + jj] = acc[jj] * inv + b2[l4 * 8 + jj];
    }
}

extern "C" void kernel_launch(void* const* d_in, const int* in_sizes, int n_in,
                              void* d_out, int out_size, void* d_ws, size_t ws_size,
                              hipStream_t stream) {
    const float* h   = (const float*)d_in[0];
    const int*   src = (const int*)d_in[1];
    const int*   dst = (const int*)d_in[2];
    const float* W1  = (const float*)d_in[3];
    const float* al1 = (const float*)d_in[4];
    const float* ar1 = (const float*)d_in[5];
    const float* b1  = (const float*)d_in[6];
    const float* W2  = (const float*)d_in[7];
    const float* al2 = (const float*)d_in[8];
    const float* ar2 = (const float*)d_in[9];
    const float* b2  = (const float*)d_in[10];
    float* out = (float*)d_out;
    const int N = NN;
    const int E = in_sizes[1];

    char* w = (char*)d_ws;
    __half* z1h       = (__half*)w;   w += (size_t)N * 128 * 2;
    __half* z2h       = (__half*)w;   w += (size_t)N * 32 * 2;
    int2*  ebuf       = (int2*)w;     w += (size_t)NBUCK * BCAP * 8;
    float4* alpha1v   = (float4*)w;   w += (size_t)E * 16;
    int*   src_sorted = (int*)w;      w += (size_t)E * 4;
    float* el1        = (float*)w;    w += (size_t)N * 4 * 4;
    float* er1        = (float*)w;    w += (size_t)N * 4 * 4;
    float* el2        = (float*)w;    w += (size_t)N * 4;
    float* er2        = (float*)w;    w += (size_t)N * 4;
    unsigned* off     = (unsigned*)w; w += (size_t)(N + 16) * 4;
    unsigned* bucket_cursor = (unsigned*)w; w += 128 * 4;

    zero_kernel<<<1, 128, 0, stream>>>(bucket_cursor);
    bucketA<<<(E + 1023) / 1024, 1024, 0, stream>>>(src, dst, bucket_cursor, ebuf, E);
    gemm1_kernel<<<(N + TM - 1) / TM, 128, 0, stream>>>(h, W1, al1, ar1, z1h, el1, er1, N);
    scatterC<<<NBUCK, 1024, 0, stream>>>(ebuf, bucket_cursor, el1, er1,
                                         off, src_sorted, alpha1v, N, E);
    agg1_fused<<<N / 4, 256, 0, stream>>>(src_sorted, off, (const float*)alpha1v, z1h, b1,
                                          W2, al2, ar2, z2h, el2, er2);
    agg2_fused<<<N / 4, 256, 0, stream>>>(src_sorted, off, el2, er2, z2h, b2, out);
}

// Round 10
// 322.127 us; speedup vs baseline: 5.7746x; 1.0564x over previous
//
#include <hip/hip_runtime.h>
#include <hip/hip_fp16.h>

#define NN 50000
#define NEG_SLOPE 0.2f
#define BSHIFT 9
#define BNODES (1 << BSHIFT)                          // 512 nodes per bucket
#define NBUCK ((NN + BNODES - 1) >> BSHIFT)           // 98
#define BCAP 18432                                    // E/NBUCK=16384 avg, +16 sigma

// ---- init: bucket cursors to region starts ----
__global__ void zero_kernel(unsigned* bucket_cursor) {
    int i = threadIdx.x;
    if (i < NBUCK) bucket_cursor[i] = (unsigned)(i * BCAP);
}

// ---- pass A: coarse bucket binning of (src,dst) by dst>>9 (low regs, no spill) ----
__global__ __launch_bounds__(1024) void bucketA(
        const int* __restrict__ src, const int* __restrict__ dst,
        unsigned* __restrict__ bucket_cursor, int2* __restrict__ ebuf, int E) {
    __shared__ unsigned hist[NBUCK];
    int tid = threadIdx.x;
    if (tid < NBUCK) hist[tid] = 0u;
    __syncthreads();
    int e = blockIdx.x * 1024 + tid;
    int s = 0, d = 0, b = 0;
    bool valid = e < E;
    if (valid) {
        s = src[e]; d = dst[e]; b = d >> BSHIFT;
        atomicAdd(&hist[b], 1u);
    }
    __syncthreads();
    if (tid < NBUCK) {
        unsigned c = hist[tid];
        hist[tid] = c ? atomicAdd(&bucket_cursor[tid], c) : 0u;
    }
    __syncthreads();
    if (valid) {
        unsigned slot = atomicAdd(&hist[b], 1u);
        ebuf[slot] = make_int2(s, d);
    }
}

// ===== z1 = h @ W1 (fp16 out) + el1/er1 — register-tiled: 32x128 block, 4x4/thread =====
// thread (gc = tid&31, gr = tid>>5): rows gr*4..+3, cols gc+32i (i = head i!)
__global__ __launch_bounds__(256) void gemm1_kernel(
        const float* __restrict__ h, const float* __restrict__ W1,
        const float* __restrict__ al1, const float* __restrict__ ar1,
        __half* __restrict__ z1h, float* __restrict__ el1, float* __restrict__ er1, int N) {
    __shared__ float hs[32 * 132];    // row stride 132: bank spread for 8 distinct rows
    __shared__ float wT[128 * 36];    // [col][k-panel 32], stride 36: bank spread
    int tid = threadIdx.x;
    int gc = tid & 31, gr = tid >> 5;
    int row0 = blockIdx.x * 32;
    int nrow = min(32, N - row0);

    for (int idx = tid; idx < nrow * 32; idx += 256) {
        int row = idx >> 5, kq = idx & 31;
        *(float4*)&hs[row * 132 + kq * 4] =
            ((const float4*)(h + (size_t)(row0 + row) * 128))[kq];
    }

    float acc[4][4];
    #pragma unroll
    for (int j = 0; j < 4; ++j)
        #pragma unroll
        for (int i = 0; i < 4; ++i) acc[j][i] = 0.f;

    for (int p = 0; p < 4; ++p) {                 // K-panels of 32
        __syncthreads();                          // protect wT reuse (also covers hs 1st time)
        for (int idx = tid; idx < 1024; idx += 256) {
            int col = idx & 127, kq = idx >> 7;   // kq 0..7
            int k0 = p * 32 + kq * 4;
            float4 wv;
            wv.x = W1[(k0 + 0) * 128 + col];
            wv.y = W1[(k0 + 1) * 128 + col];
            wv.z = W1[(k0 + 2) * 128 + col];
            wv.w = W1[(k0 + 3) * 128 + col];
            *(float4*)&wT[col * 36 + kq * 4] = wv;
        }
        __syncthreads();
        #pragma unroll
        for (int kq = 0; kq < 8; ++kq) {
            float4 wv[4], hv[4];
            #pragma unroll
            for (int i = 0; i < 4; ++i) wv[i] = *(const float4*)&wT[(gc + 32 * i) * 36 + kq * 4];
            #pragma unroll
            for (int j = 0; j < 4; ++j) hv[j] = *(const float4*)&hs[(gr * 4 + j) * 132 + p * 32 + kq * 4];
            #pragma unroll
            for (int j = 0; j < 4; ++j)
                #pragma unroll
                for (int i = 0; i < 4; ++i)
                    acc[j][i] = fmaf(hv[j].x, wv[i].x, fmaf(hv[j].y, wv[i].y,
                                fmaf(hv[j].z, wv[i].z, fmaf(hv[j].w, wv[i].w, acc[j][i]))));
        }
    }

    float a_l[4], a_r[4];
    #pragma unroll
    for (int i = 0; i < 4; ++i) { a_l[i] = al1[gc + 32 * i]; a_r[i] = ar1[gc + 32 * i]; }

    #pragma unroll
    for (int j = 0; j < 4; ++j) {
        int row = gr * 4 + j;
        bool live = row < nrow;
        int node = row0 + row;
        if (live) {
            #pragma unroll
            for (int i = 0; i < 4; ++i)
                z1h[(size_t)node * 128 + gc + 32 * i] = __float2half(acc[j][i]);
        }
        float pl[4], pr[4];
        #pragma unroll
        for (int i = 0; i < 4; ++i) { pl[i] = acc[j][i] * a_l[i]; pr[i] = acc[j][i] * a_r[i]; }
        #pragma unroll
        for (int o = 16; o; o >>= 1) {
            #pragma unroll
            for (int i = 0; i < 4; ++i) {
                pl[i] += __shfl_xor(pl[i], o, 32);
                pr[i] += __shfl_xor(pr[i], o, 32);
            }
        }
        if (live && gc == 0) {
            #pragma unroll
            for (int i = 0; i < 4; ++i) {
                el1[node * 4 + i] = pl[i];
                er1[node * 4 + i] = pr[i];
            }
        }
    }
}

// ---- scatterC: inline bucket scan + per-bucket LDS hist/scan/rank;
//      writes off[], src_sorted[], and per-edge alpha1 (exp of leaky score, 4 heads) ----
__global__ __launch_bounds__(1024) void scatterC(
        const int2* __restrict__ ebuf, const unsigned* __restrict__ bucket_cursor,
        const float* __restrict__ el1, const float* __restrict__ er1,
        unsigned* __restrict__ off, int* __restrict__ src_sorted,
        float4* __restrict__ alpha1v, int N, int E) {
    __shared__ unsigned hist[BNODES], nodeoff[BNODES], wsum[8], bsz[128];
    __shared__ float4 er_s[BNODES];
    int b = blockIdx.x, tid = threadIdx.x;
    int base = b << BSHIFT;
    unsigned rs = (unsigned)(b * BCAP), re = bucket_cursor[b];
    const float4* el1v = (const float4*)el1;
    const float4* er1v = (const float4*)er1;

    if (tid < 128) bsz[tid] = (tid < NBUCK) ? bucket_cursor[tid] - (unsigned)(tid * BCAP) : 0u;
    if (tid < BNODES) {
        hist[tid] = 0u;
        int n = base + tid;
        er_s[tid] = (n < N) ? er1v[n] : make_float4(0.f, 0.f, 0.f, 0.f);
    }
    __syncthreads();
    if (tid == 0) {
        unsigned r = 0;
        for (int t = 0; t < NBUCK; ++t) { unsigned c = bsz[t]; bsz[t] = r; r += c; }
        if (b == 0) off[N] = (unsigned)E;
    }
    __syncthreads();
    unsigned boff = bsz[b];

    for (unsigned i = rs + tid; i < re; i += 1024)
        atomicAdd(&hist[ebuf[i].y - base], 1u);
    __syncthreads();
    unsigned v = 0, x = 0;
    int lane = tid & 63, wv = tid >> 6;
    if (tid < BNODES) {
        v = hist[tid]; x = v;
        #pragma unroll
        for (int o = 1; o < 64; o <<= 1) {
            unsigned n = __shfl_up(x, o, 64);
            if (lane >= o) x += n;
        }
        if (lane == 63) wsum[wv] = x;
    }
    __syncthreads();
    if (tid == 0) {
        unsigned r = 0;
        #pragma unroll
        for (int k = 0; k < 8; ++k) { unsigned t = wsum[k]; wsum[k] = r; r += t; }
    }
    __syncthreads();
    if (tid < BNODES) {
        unsigned exoff = x - v + wsum[wv] + boff;
        nodeoff[tid] = exoff;
        if (base + tid < N) off[base + tid] = exoff;
        hist[tid] = 0u;
    }
    __syncthreads();
    // rank + write src_sorted and alpha (softmax shift dropped: scores bounded, exp-safe)
    for (unsigned i = rs + tid; i < re; i += 1024) {
        int2 ed = ebuf[i];
        int ln = ed.y - base;
        unsigned r = atomicAdd(&hist[ln], 1u);
        unsigned p = nodeoff[ln] + r;
        src_sorted[p] = ed.x;
        float4 el = el1v[ed.x];
        float4 er = er_s[ln];
        float v0 = el.x + er.x; v0 = v0 > 0.f ? v0 : NEG_SLOPE * v0;
        float v1 = el.y + er.y; v1 = v1 > 0.f ? v1 : NEG_SLOPE * v1;
        float v2 = el.z + er.z; v2 = v2 > 0.f ? v2 : NEG_SLOPE * v2;
        float v3 = el.w + er.w; v3 = v3 > 0.f ? v3 : NEG_SLOPE * v3;
        alpha1v[p] = make_float4(__expf(v0), __expf(v1), __expf(v2), __expf(v3));
    }
}

// ====== layer1: pure SpMM (alpha precomputed, position-indexed) + elu + gemm2 ======
__global__ __launch_bounds__(256) void agg1_fused(
        const int* __restrict__ src_sorted, const unsigned* __restrict__ off,
        const float* __restrict__ alpha1, const __half* __restrict__ z1h,
        const float* __restrict__ b1, const float* __restrict__ W2,
        const float* __restrict__ al2, const float* __restrict__ ar2,
        __half* __restrict__ z2h, float* __restrict__ el2, float* __restrict__ er2) {
    __shared__ float W2s[128 * 32];
    __shared__ float xs[4][128];
    int tid = threadIdx.x, lane = tid & 63, w = tid >> 6;
    {
        const float4* s4 = (const float4*)W2;
        float4* d4 = (float4*)W2s;
        #pragma unroll
        for (int k = 0; k < 4; ++k) d4[tid + 256 * k] = s4[tid + 256 * k];
    }

    int node = blockIdx.x * 4 + w;
    int start = (int)off[node], end = (int)off[node + 1];
    int g = lane >> 4, l16 = lane & 15, head = l16 >> 2, j = l16 & 3;

    float acc[8];
    #pragma unroll
    for (int jj = 0; jj < 8; ++jj) acc[jj] = 0.f;
    float sloc = 0.f;
    int endm1 = end - 1;
    for (int base = start; base < end; base += 32) {
        #pragma unroll
        for (int t = 0; t < 8; ++t) {               // 32 edges in flight per wave-iter
            int i = base + 4 * t + g;
            int ic = min(i, endm1);                 // clamped: always valid
            int s = src_sorted[ic];
            float a = alpha1[ic * 4 + head];        // position-indexed: independent of s
            a = (i < end) ? a : 0.f;                // select, not branch
            sloc += (j == 0) ? a : 0.f;
            float4 r = *(const float4*)(z1h + ((size_t)s << 7) + l16 * 8);
            const __half* zh = (const __half*)&r;
            #pragma unroll
            for (int k = 0; k < 8; ++k)             // v_fma_mix_f32
                acc[k] = fmaf(__half2float(zh[k]), a, acc[k]);
        }
    }
    #pragma unroll
    for (int jj = 0; jj < 8; ++jj) {
        acc[jj] += __shfl_xor(acc[jj], 16, 64);
        acc[jj] += __shfl_xor(acc[jj], 32, 64);
    }
    sloc += __shfl_xor(sloc, 1, 64);
    sloc += __shfl_xor(sloc, 2, 64);
    sloc += __shfl_xor(sloc, 16, 64);
    sloc += __shfl_xor(sloc, 32, 64);
    float inv = sloc > 0.f ? 1.f / sloc : 0.f;

    if (g == 0) {
        #pragma unroll
        for (int jj = 0; jj < 8; ++jj) {
            float x = acc[jj] * inv + b1[l16 * 8 + jj];
            x = x > 0.f ? x : (__expf(x) - 1.f);   // elu
            xs[w][l16 * 8 + jj] = x;
        }
    }
    __syncthreads();   // covers W2s staging + xs

    int c = lane & 31, q = lane >> 5;
    float p = 0.f;
    for (int kk = 0; kk < 64; kk += 4) {
        int k = q * 64 + kk;
        float4 xv = *(const float4*)&xs[w][k];     // ds_read_b128
        p = fmaf(xv.x, W2s[k * 32 + c],
            fmaf(xv.y, W2s[(k + 1) * 32 + c],
            fmaf(xv.z, W2s[(k + 2) * 32 + c],
            fmaf(xv.w, W2s[(k + 3) * 32 + c], p))));
    }
    p += __shfl_xor(p, 32, 64);
    if (lane < 32) {
        z2h[(size_t)node * 32 + c] = __float2half(p);
        float pl = p * al2[c], pr = p * ar2[c];
        #pragma unroll
        for (int o = 16; o; o >>= 1) {
            pl += __shfl_xor(pl, o, 32);
            pr += __shfl_xor(pr, o, 32);
        }
        if (c == 0) { el2[node] = pl; er2[node] = pr; }
    }
}

// ====== layer2: single-pass exp + SpMM (fma_mix) + bias -> out (wave/node) ======
__global__ __launch_bounds__(256) void agg2_fused(
        const int* __restrict__ src_sorted, const unsigned* __restrict__ off,
        const float* __restrict__ el2, const float* __restrict__ er2,
        const __half* __restrict__ z2h, const float* __restrict__ b2,
        float* __restrict__ out) {
    int tid = threadIdx.x, lane = tid & 63;
    int node = blockIdx.x * 4 + (tid >> 6);
    int start = (int)off[node], end = (int)off[node + 1];
    float er_d = er2[node];

    int g = lane >> 2, l4 = lane & 3;
    float acc[8];
    #pragma unroll
    for (int jj = 0; jj < 8; ++jj) acc[jj] = 0.f;
    float sloc = 0.f;
    int endm1 = end - 1;
    for (int base = start; base < end; base += 64) {
        #pragma unroll
        for (int t = 0; t < 4; ++t) {               // 64 edges in flight per wave-iter
            int i = base + 16 * t + g;
            int ic = min(i, endm1);
            int s = src_sorted[ic];
            float v = el2[s] + er_d;
            v = v > 0.f ? v : NEG_SLOPE * v;
            float ex = __expf(v);
            ex = (i < end) ? ex : 0.f;
            sloc += (l4 == 0) ? ex : 0.f;
            float4 r = *(const float4*)(z2h + ((size_t)s << 5) + l4 * 8);
            const __half* zh = (const __half*)&r;
            #pragma unroll
            for (int k = 0; k < 8; ++k)
                acc[k] = fmaf(__half2float(zh[k]), ex, acc[k]);
        }
    }
    #pragma unroll
    for (int jj = 0; jj < 8; ++jj) {
        acc[jj] += __shfl_xor(acc[jj], 4, 64);
        acc[jj] += __shfl_xor(acc[jj], 8, 64);
        acc[jj] += __shfl_xor(acc[jj], 16, 64);
        acc[jj] += __shfl_xor(acc[jj], 32, 64);
    }
    #pragma unroll
    for (int o = 32; o; o >>= 1) sloc += __shfl_xor(sloc, o, 64);
    float inv = sloc > 0.f ? 1.f / sloc : 0.f;
    if (g == 0) {
        #pragma unroll
        for (int jj = 0; jj < 8; ++jj)
            out[(size_t)node * 32 + l4 * 8 + jj] = acc[jj] * inv + b2[l4 * 8 + jj];
    }
}

extern "C" void kernel_launch(void* const* d_in, const int* in_sizes, int n_in,
                              void* d_out, int out_size, void* d_ws, size_t ws_size,
                              hipStream_t stream) {
    const float* h   = (const float*)d_in[0];
    const int*   src = (const int*)d_in[1];
    const int*   dst = (const int*)d_in[2];
    const float* W1  = (const float*)d_in[3];
    const float* al1 = (const float*)d_in[4];
    const float* ar1 = (const float*)d_in[5];
    const float* b1  = (const float*)d_in[6];
    const float* W2  = (const float*)d_in[7];
    const float* al2 = (const float*)d_in[8];
    const float* ar2 = (const float*)d_in[9];
    const float* b2  = (const float*)d_in[10];
    float* out = (float*)d_out;
    const int N = NN;
    const int E = in_sizes[1];

    char* w = (char*)d_ws;
    __half* z1h       = (__half*)w;   w += (size_t)N * 128 * 2;
    __half* z2h       = (__half*)w;   w += (size_t)N * 32 * 2;
    int2*  ebuf       = (int2*)w;     w += (size_t)NBUCK * BCAP * 8;
    float4* alpha1v   = (float4*)w;   w += (size_t)E * 16;
    int*   src_sorted = (int*)w;      w += (size_t)E * 4;
    float* el1        = (float*)w;    w += (size_t)N * 4 * 4;
    float* er1        = (float*)w;    w += (size_t)N * 4 * 4;
    float* el2        = (float*)w;    w += (size_t)N * 4;
    float* er2        = (float*)w;    w += (size_t)N * 4;
    unsigned* off     = (unsigned*)w; w += (size_t)(N + 16) * 4;
    unsigned* bucket_cursor = (unsigned*)w; w += 128 * 4;

    zero_kernel<<<1, 128, 0, stream>>>(bucket_cursor);
    bucketA<<<(E + 1023) / 1024, 1024, 0, stream>>>(src, dst, bucket_cursor, ebuf, E);
    gemm1_kernel<<<(N + 31) / 32, 256, 0, stream>>>(h, W1, al1, ar1, z1h, el1, er1, N);
    scatterC<<<NBUCK, 1024, 0, stream>>>(ebuf, bucket_cursor, el1, er1,
                                         off, src_sorted, alpha1v, N, E);
    agg1_fused<<<N / 4, 256, 0, stream>>>(src_sorted, off, (const float*)alpha1v, z1h, b1,
                                          W2, al2, ar2, z2h, el2, er2);
    agg2_fused<<<N / 4, 256, 0, stream>>>(src_sorted, off, el2, er2, z2h, b2, out);
}

// Round 11
// 316.946 us; speedup vs baseline: 5.8690x; 1.0163x over previous
//
#include <hip/hip_runtime.h>
#include <hip/hip_fp16.h>

#define NN 50000
#define NEG_SLOPE 0.2f
#define BSHIFT 9
#define BNODES (1 << BSHIFT)                          // 512 nodes per bucket
#define NBUCK ((NN + BNODES - 1) >> BSHIFT)           // 98
#define BCAP 18432                                    // E/NBUCK=16384 avg, +16 sigma

// ---- init: bucket cursors to region starts ----
__global__ void zero_kernel(unsigned* bucket_cursor) {
    int i = threadIdx.x;
    if (i < NBUCK) bucket_cursor[i] = (unsigned)(i * BCAP);
}

// ---- pass A: coarse bucket binning of (src,dst) by dst>>9 (low regs, no spill) ----
__global__ __launch_bounds__(1024) void bucketA(
        const int* __restrict__ src, const int* __restrict__ dst,
        unsigned* __restrict__ bucket_cursor, int2* __restrict__ ebuf, int E) {
    __shared__ unsigned hist[NBUCK];
    int tid = threadIdx.x;
    if (tid < NBUCK) hist[tid] = 0u;
    __syncthreads();
    int e = blockIdx.x * 1024 + tid;
    int s = 0, d = 0, b = 0;
    bool valid = e < E;
    if (valid) {
        s = src[e]; d = dst[e]; b = d >> BSHIFT;
        atomicAdd(&hist[b], 1u);
    }
    __syncthreads();
    if (tid < NBUCK) {
        unsigned c = hist[tid];
        hist[tid] = c ? atomicAdd(&bucket_cursor[tid], c) : 0u;
    }
    __syncthreads();
    if (valid) {
        unsigned slot = atomicAdd(&hist[b], 1u);
        ebuf[slot] = make_int2(s, d);
    }
}

// ===== z1 = h @ W1 (fp16 out) + el1/er1 — register-tiled: 32x128 block, 4x4/thread =====
__global__ __launch_bounds__(256) void gemm1_kernel(
        const float* __restrict__ h, const float* __restrict__ W1,
        const float* __restrict__ al1, const float* __restrict__ ar1,
        __half* __restrict__ z1h, float* __restrict__ el1, float* __restrict__ er1, int N) {
    __shared__ float hs[32 * 132];    // row stride 132: bank spread
    __shared__ float wT[128 * 36];    // [col][k-panel 32], stride 36
    int tid = threadIdx.x;
    int gc = tid & 31, gr = tid >> 5;
    int row0 = blockIdx.x * 32;
    int nrow = min(32, N - row0);

    for (int idx = tid; idx < nrow * 32; idx += 256) {
        int row = idx >> 5, kq = idx & 31;
        *(float4*)&hs[row * 132 + kq * 4] =
            ((const float4*)(h + (size_t)(row0 + row) * 128))[kq];
    }

    float acc[4][4];
    #pragma unroll
    for (int j = 0; j < 4; ++j)
        #pragma unroll
        for (int i = 0; i < 4; ++i) acc[j][i] = 0.f;

    for (int p = 0; p < 4; ++p) {                 // K-panels of 32
        __syncthreads();
        for (int idx = tid; idx < 1024; idx += 256) {
            int col = idx & 127, kq = idx >> 7;
            int k0 = p * 32 + kq * 4;
            float4 wv;
            wv.x = W1[(k0 + 0) * 128 + col];
            wv.y = W1[(k0 + 1) * 128 + col];
            wv.z = W1[(k0 + 2) * 128 + col];
            wv.w = W1[(k0 + 3) * 128 + col];
            *(float4*)&wT[col * 36 + kq * 4] = wv;
        }
        __syncthreads();
        #pragma unroll
        for (int kq = 0; kq < 8; ++kq) {
            float4 wv[4], hv[4];
            #pragma unroll
            for (int i = 0; i < 4; ++i) wv[i] = *(const float4*)&wT[(gc + 32 * i) * 36 + kq * 4];
            #pragma unroll
            for (int j = 0; j < 4; ++j) hv[j] = *(const float4*)&hs[(gr * 4 + j) * 132 + p * 32 + kq * 4];
            #pragma unroll
            for (int j = 0; j < 4; ++j)
                #pragma unroll
                for (int i = 0; i < 4; ++i)
                    acc[j][i] = fmaf(hv[j].x, wv[i].x, fmaf(hv[j].y, wv[i].y,
                                fmaf(hv[j].z, wv[i].z, fmaf(hv[j].w, wv[i].w, acc[j][i]))));
        }
    }

    float a_l[4], a_r[4];
    #pragma unroll
    for (int i = 0; i < 4; ++i) { a_l[i] = al1[gc + 32 * i]; a_r[i] = ar1[gc + 32 * i]; }

    #pragma unroll
    for (int j = 0; j < 4; ++j) {
        int row = gr * 4 + j;
        bool live = row < nrow;
        int node = row0 + row;
        if (live) {
            #pragma unroll
            for (int i = 0; i < 4; ++i)
                z1h[(size_t)node * 128 + gc + 32 * i] = __float2half(acc[j][i]);
        }
        float pl[4], pr[4];
        #pragma unroll
        for (int i = 0; i < 4; ++i) { pl[i] = acc[j][i] * a_l[i]; pr[i] = acc[j][i] * a_r[i]; }
        #pragma unroll
        for (int o = 16; o; o >>= 1) {
            #pragma unroll
            for (int i = 0; i < 4; ++i) {
                pl[i] += __shfl_xor(pl[i], o, 32);
                pr[i] += __shfl_xor(pr[i], o, 32);
            }
        }
        if (live && gc == 0) {
            #pragma unroll
            for (int i = 0; i < 4; ++i) {
                el1[node * 4 + i] = pl[i];
                er1[node * 4 + i] = pr[i];
            }
        }
    }
}

// ---- scatterC: per-bucket LDS hist/scan/rank; writes off[], src_sorted[],
//      and per-edge alpha1 as fp16 half4 (exp of leaky score, 4 heads) ----
__global__ __launch_bounds__(1024) void scatterC(
        const int2* __restrict__ ebuf, const unsigned* __restrict__ bucket_cursor,
        const float* __restrict__ el1, const float* __restrict__ er1,
        unsigned* __restrict__ off, int* __restrict__ src_sorted,
        uint2* __restrict__ alpha1p, int N, int E) {
    __shared__ unsigned hist[BNODES], nodeoff[BNODES], wsum[8], bsz[128];
    __shared__ float4 er_s[BNODES];
    int b = blockIdx.x, tid = threadIdx.x;
    int base = b << BSHIFT;
    unsigned rs = (unsigned)(b * BCAP), re = bucket_cursor[b];
    const float4* el1v = (const float4*)el1;
    const float4* er1v = (const float4*)er1;

    if (tid < 128) bsz[tid] = (tid < NBUCK) ? bucket_cursor[tid] - (unsigned)(tid * BCAP) : 0u;
    if (tid < BNODES) {
        hist[tid] = 0u;
        int n = base + tid;
        er_s[tid] = (n < N) ? er1v[n] : make_float4(0.f, 0.f, 0.f, 0.f);
    }
    __syncthreads();
    if (tid == 0) {
        unsigned r = 0;
        for (int t = 0; t < NBUCK; ++t) { unsigned c = bsz[t]; bsz[t] = r; r += c; }
        if (b == 0) off[N] = (unsigned)E;
    }
    __syncthreads();
    unsigned boff = bsz[b];

    for (unsigned i = rs + tid; i < re; i += 1024)
        atomicAdd(&hist[ebuf[i].y - base], 1u);
    __syncthreads();
    unsigned v = 0, x = 0;
    int lane = tid & 63, wv = tid >> 6;
    if (tid < BNODES) {
        v = hist[tid]; x = v;
        #pragma unroll
        for (int o = 1; o < 64; o <<= 1) {
            unsigned n = __shfl_up(x, o, 64);
            if (lane >= o) x += n;
        }
        if (lane == 63) wsum[wv] = x;
    }
    __syncthreads();
    if (tid == 0) {
        unsigned r = 0;
        #pragma unroll
        for (int k = 0; k < 8; ++k) { unsigned t = wsum[k]; wsum[k] = r; r += t; }
    }
    __syncthreads();
    if (tid < BNODES) {
        unsigned exoff = x - v + wsum[wv] + boff;
        nodeoff[tid] = exoff;
        if (base + tid < N) off[base + tid] = exoff;
        hist[tid] = 0u;
    }
    __syncthreads();
    // rank + write src_sorted and alpha (softmax shift dropped: scores bounded, exp-safe;
    // alpha quantized to fp16 ONCE here, normalization downstream uses the same values)
    for (unsigned i = rs + tid; i < re; i += 1024) {
        int2 ed = ebuf[i];
        int ln = ed.y - base;
        unsigned r = atomicAdd(&hist[ln], 1u);
        unsigned p = nodeoff[ln] + r;
        src_sorted[p] = ed.x;
        float4 el = el1v[ed.x];
        float4 er = er_s[ln];
        float v0 = el.x + er.x; v0 = v0 > 0.f ? v0 : NEG_SLOPE * v0;
        float v1 = el.y + er.y; v1 = v1 > 0.f ? v1 : NEG_SLOPE * v1;
        float v2 = el.z + er.z; v2 = v2 > 0.f ? v2 : NEG_SLOPE * v2;
        float v3 = el.w + er.w; v3 = v3 > 0.f ? v3 : NEG_SLOPE * v3;
        union { __half2 h2[2]; uint2 u; } pk;
        pk.h2[0] = __floats2half2_rn(__expf(v0), __expf(v1));
        pk.h2[1] = __floats2half2_rn(__expf(v2), __expf(v3));
        alpha1p[p] = pk.u;
    }
}

// ====== layer1: pure gather-SpMM + normalize + bias + elu -> x (fp16). No LDS. ======
__global__ __launch_bounds__(256) void agg1_spmm(
        const int* __restrict__ src_sorted, const unsigned* __restrict__ off,
        const __half* __restrict__ alpha1h, const __half* __restrict__ z1h,
        const float* __restrict__ b1, __half* __restrict__ x) {
    int tid = threadIdx.x, lane = tid & 63, w = tid >> 6;
    int node = blockIdx.x * 4 + w;
    int start = (int)off[node], end = (int)off[node + 1];
    int g = lane >> 4, l16 = lane & 15, head = l16 >> 2, j = l16 & 3;

    float acc[8];
    #pragma unroll
    for (int jj = 0; jj < 8; ++jj) acc[jj] = 0.f;
    float sloc = 0.f;
    int endm1 = end - 1;
    for (int base = start; base < end; base += 32) {
        #pragma unroll
        for (int t = 0; t < 8; ++t) {               // 32 edges in flight per wave-iter
            int i = base + 4 * t + g;
            int ic = min(i, endm1);                 // clamped: always valid
            int s = src_sorted[ic];
            float a = __half2float(alpha1h[ic * 4 + head]);  // position-indexed
            a = (i < end) ? a : 0.f;                // select, not branch
            sloc += (j == 0) ? a : 0.f;
            float4 r = *(const float4*)(z1h + ((size_t)s << 7) + l16 * 8);
            const __half* zh = (const __half*)&r;
            #pragma unroll
            for (int k = 0; k < 8; ++k)             // v_fma_mix_f32
                acc[k] = fmaf(__half2float(zh[k]), a, acc[k]);
        }
    }
    #pragma unroll
    for (int jj = 0; jj < 8; ++jj) {
        acc[jj] += __shfl_xor(acc[jj], 16, 64);
        acc[jj] += __shfl_xor(acc[jj], 32, 64);
    }
    sloc += __shfl_xor(sloc, 1, 64);
    sloc += __shfl_xor(sloc, 2, 64);
    sloc += __shfl_xor(sloc, 16, 64);
    sloc += __shfl_xor(sloc, 32, 64);
    float inv = sloc > 0.f ? 1.f / sloc : 0.f;

    if (g == 0) {
        float xv[8];
        #pragma unroll
        for (int jj = 0; jj < 8; ++jj) {
            float t = acc[jj] * inv + b1[l16 * 8 + jj];
            xv[jj] = t > 0.f ? t : (__expf(t) - 1.f);   // elu
        }
        union { __half2 h2[4]; uint4 u; } pk;
        #pragma unroll
        for (int k = 0; k < 4; ++k) pk.h2[k] = __floats2half2_rn(xv[2 * k], xv[2 * k + 1]);
        *(uint4*)(x + ((size_t)node << 7) + l16 * 8) = pk.u;
    }
}

// ===== z2 = x @ W2 (fp16 in/out) + el2/er2 — 64 rows/block, 4 rows x 2 cols/thread =====
__global__ __launch_bounds__(256) void gemm2el_kernel(
        const __half* __restrict__ x, const float* __restrict__ W2,
        const float* __restrict__ al2, const float* __restrict__ ar2,
        __half* __restrict__ z2h, float* __restrict__ el2, float* __restrict__ er2, int N) {
    __shared__ __half xsh[64][136];   // pad 8 halves
    __shared__ float W2T[32][132];    // [c][k]
    int tid = threadIdx.x;
    int row0 = blockIdx.x * 64;
    int nrow = min(64, N - row0);

    for (int idx = tid; idx < nrow * 16; idx += 256) {
        int r = idx >> 4, kq = idx & 15;
        float4 v = ((const float4*)(x + (size_t)(row0 + r) * 128))[kq];
        *(float4*)&xsh[r][kq * 8] = v;
    }
    for (int idx = tid; idx < 4096; idx += 256) {
        int k = idx >> 5, c = idx & 31;
        W2T[c][k] = W2[idx];
    }
    __syncthreads();

    int gc = tid & 15, gr = tid >> 4;   // rows gr*4+j, cols {gc, gc+16}
    float acc[4][2];
    #pragma unroll
    for (int j = 0; j < 4; ++j) { acc[j][0] = 0.f; acc[j][1] = 0.f; }

    for (int p = 0; p < 32; ++p) {      // k-chunks of 4
        float4 w0 = *(const float4*)&W2T[gc][p * 4];
        float4 w1 = *(const float4*)&W2T[gc + 16][p * 4];
        #pragma unroll
        for (int j = 0; j < 4; ++j) {
            const __half* xr = &xsh[gr * 4 + j][p * 4];
            float x0 = __half2float(xr[0]), x1 = __half2float(xr[1]);
            float x2 = __half2float(xr[2]), x3 = __half2float(xr[3]);
            acc[j][0] = fmaf(x0, w0.x, fmaf(x1, w0.y, fmaf(x2, w0.z, fmaf(x3, w0.w, acc[j][0]))));
            acc[j][1] = fmaf(x0, w1.x, fmaf(x1, w1.y, fmaf(x2, w1.z, fmaf(x3, w1.w, acc[j][1]))));
        }
    }

    float al0 = al2[gc], al1v = al2[gc + 16];
    float ar0 = ar2[gc], ar1v = ar2[gc + 16];
    #pragma unroll
    for (int j = 0; j < 4; ++j) {
        int r = gr * 4 + j;
        int node = row0 + r;
        bool live = r < nrow;
        if (live) {
            z2h[(size_t)node * 32 + gc]      = __float2half(acc[j][0]);
            z2h[(size_t)node * 32 + gc + 16] = __float2half(acc[j][1]);
        }
        float pl = acc[j][0] * al0 + acc[j][1] * al1v;
        float pr = acc[j][0] * ar0 + acc[j][1] * ar1v;
        #pragma unroll
        for (int o = 8; o; o >>= 1) {
            pl += __shfl_xor(pl, o, 16);
            pr += __shfl_xor(pr, o, 16);
        }
        if (live && gc == 0) { el2[node] = pl; er2[node] = pr; }
    }
}

// ====== layer2: single-pass exp + SpMM (fma_mix) + bias -> out (wave/node) ======
__global__ __launch_bounds__(256) void agg2_fused(
        const int* __restrict__ src_sorted, const unsigned* __restrict__ off,
        const float* __restrict__ el2, const float* __restrict__ er2,
        const __half* __restrict__ z2h, const float* __restrict__ b2,
        float* __restrict__ out) {
    int tid = threadIdx.x, lane = tid & 63;
    int node = blockIdx.x * 4 + (tid >> 6);
    int start = (int)off[node], end = (int)off[node + 1];
    float er_d = er2[node];

    int g = lane >> 2, l4 = lane & 3;
    float acc[8];
    #pragma unroll
    for (int jj = 0; jj < 8; ++jj) acc[jj] = 0.f;
    float sloc = 0.f;
    int endm1 = end - 1;
    for (int base = start; base < end; base += 64) {
        #pragma unroll
        for (int t = 0; t < 4; ++t) {               // 64 edges in flight per wave-iter
            int i = base + 16 * t + g;
            int ic = min(i, endm1);
            int s = src_sorted[ic];
            float v = el2[s] + er_d;
            v = v > 0.f ? v : NEG_SLOPE * v;
            float ex = __expf(v);
            ex = (i < end) ? ex : 0.f;
            sloc += (l4 == 0) ? ex : 0.f;
            float4 r = *(const float4*)(z2h + ((size_t)s << 5) + l4 * 8);
            const __half* zh = (const __half*)&r;
            #pragma unroll
            for (int k = 0; k < 8; ++k)
                acc[k] = fmaf(__half2float(zh[k]), ex, acc[k]);
        }
    }
    #pragma unroll
    for (int jj = 0; jj < 8; ++jj) {
        acc[jj] += __shfl_xor(acc[jj], 4, 64);
        acc[jj] += __shfl_xor(acc[jj], 8, 64);
        acc[jj] += __shfl_xor(acc[jj], 16, 64);
        acc[jj] += __shfl_xor(acc[jj], 32, 64);
    }
    #pragma unroll
    for (int o = 32; o; o >>= 1) sloc += __shfl_xor(sloc, o, 64);
    float inv = sloc > 0.f ? 1.f / sloc : 0.f;
    if (g == 0) {
        #pragma unroll
        for (int jj = 0; jj < 8; ++jj)
            out[(size_t)node * 32 + l4 * 8 + jj] = acc[jj] * inv + b2[l4 * 8 + jj];
    }
}

extern "C" void kernel_launch(void* const* d_in, const int* in_sizes, int n_in,
                              void* d_out, int out_size, void* d_ws, size_t ws_size,
                              hipStream_t stream) {
    const float* h   = (const float*)d_in[0];
    const int*   src = (const int*)d_in[1];
    const int*   dst = (const int*)d_in[2];
    const float* W1  = (const float*)d_in[3];
    const float* al1 = (const float*)d_in[4];
    const float* ar1 = (const float*)d_in[5];
    const float* b1  = (const float*)d_in[6];
    const float* W2  = (const float*)d_in[7];
    const float* al2 = (const float*)d_in[8];
    const float* ar2 = (const float*)d_in[9];
    const float* b2  = (const float*)d_in[10];
    float* out = (float*)d_out;
    const int N = NN;
    const int E = in_sizes[1];

    char* w = (char*)d_ws;
    __half* z1h       = (__half*)w;   w += (size_t)N * 128 * 2;
    __half* z2h       = (__half*)w;   w += (size_t)N * 32 * 2;
    __half* xh        = (__half*)w;   w += (size_t)N * 128 * 2;
    int2*  ebuf       = (int2*)w;     w += (size_t)NBUCK * BCAP * 8;
    uint2* alpha1p    = (uint2*)w;    w += (size_t)E * 8;
    int*   src_sorted = (int*)w;      w += (size_t)E * 4;
    float* el1        = (float*)w;    w += (size_t)N * 4 * 4;
    float* er1        = (float*)w;    w += (size_t)N * 4 * 4;
    float* el2        = (float*)w;    w += (size_t)N * 4;
    float* er2        = (float*)w;    w += (size_t)N * 4;
    unsigned* off     = (unsigned*)w; w += (size_t)(N + 16) * 4;
    unsigned* bucket_cursor = (unsigned*)w; w += 128 * 4;

    zero_kernel<<<1, 128, 0, stream>>>(bucket_cursor);
    bucketA<<<(E + 1023) / 1024, 1024, 0, stream>>>(src, dst, bucket_cursor, ebuf, E);
    gemm1_kernel<<<(N + 31) / 32, 256, 0, stream>>>(h, W1, al1, ar1, z1h, el1, er1, N);
    scatterC<<<NBUCK, 1024, 0, stream>>>(ebuf, bucket_cursor, el1, er1,
                                         off, src_sorted, alpha1p, N, E);
    agg1_spmm<<<N / 4, 256, 0, stream>>>(src_sorted, off, (const __half*)alpha1p, z1h, b1, xh);
    gemm2el_kernel<<<(N + 63) / 64, 256, 0, stream>>>(xh, W2, al2, ar2, z2h, el2, er2, N);
    agg2_fused<<<N / 4, 256, 0, stream>>>(src_sorted, off, el2, er2, z2h, b2, out);
}